// Round 6
// baseline (113.108 us; speedup 1.0000x reference)
//
#include <hip/hip_runtime.h>
#include <float.h>
#include <math.h>

#define BATCH 4
#define NPTS 4096
#define BLK 256
#define SEGN 64                    // 64 target segments of 64 points, both phases
#define TPTS 64
#define QCH 8                      // queries/thread, chamfer: LDS 1.5 vs VALU 2 cyc/pair
#define QR 4                       // queries/thread, repulsion: LDS 3 vs VALU ~6 cyc/pt
#define H2 (0.03f * 0.03f)
#define RADIUS_C 0.07f
#define EPS_C 1e-12f
#define NQ (BATCH * NPTS)          // 16384
#define NCH (2 * NQ)               // 32768 chamfer (type,b,q) rows

// d_ws layout:
//   hdr    : float accum[2] + uint cnt + pad (16 B)  @ 0  (zeroed by blk 0)
//   minseg : float [SEGN][NCH]    (8 MB)             @ 16
//   top4   : float4[SEGN][NQ]     (16 MB)            @ 16 + 8 MB
//
// d2 = (|t|^2 - 2 q.t) + |q|^2 (reference's own expansion); inner loops track
// h = |t|^2 - 2 q.t via n = -2q; +|q|^2 added at the partial store.
// R4 post-mortem: ds_read_b128 costs ~12 cyc/wave even broadcast, so the
// b128 must feed >=24 VALU insts to be VALU-bound -> QCH=8 / QR=4.
// Blocks: even bid = chamfer (2 qblk x 4 b x 2 type x 64 seg = 1024),
//         odd  bid = repulsion (4 qblk x 4 b x 64 seg = 1024); interleaved so
// both phases stay co-resident (R3's tail lesson).
__global__ __launch_bounds__(BLK) void partial_kernel(
    const float* __restrict__ pred, const float* __restrict__ gt,
    float* __restrict__ minseg, float4* __restrict__ top4,
    unsigned int* __restrict__ hdr)
{
    __shared__ float4 s[TPTS];     // (x, y, z, |t|^2), 1 KB

    if (blockIdx.x == 0 && threadIdx.x < 4)
        hdr[threadIdx.x] = 0u;     // zero accum[2]+cnt for merge

    const int bid   = blockIdx.x;
    const int isrep = bid & 1;
    const int id    = bid >> 1;    // [0, 1024)
    const int seg   = id >> 4;     // [0, 64)
    const int rest  = id & 15;

    int type, b, qblk;
    const float *qbase, *tbase;
    if (!isrep) {
        type = rest >> 3; b = (rest >> 1) & 3; qblk = rest & 1;
        qbase = type ? gt : pred; tbase = type ? pred : gt;
    } else {
        type = 2; b = rest >> 2; qblk = rest & 3;
        qbase = pred; tbase = pred;
    }

    // stage 64 targets: threads 0..31, 2 points each, |t|^2 on the fly
    if (threadIdx.x < 32) {
        const float2* g2 = (const float2*)(tbase + ((size_t)b * NPTS + seg * TPTS) * 3);
        float2 a = g2[3 * threadIdx.x + 0];
        float2 c = g2[3 * threadIdx.x + 1];
        float2 e = g2[3 * threadIdx.x + 2];
        float t20 = fmaf(a.x, a.x, fmaf(a.y, a.y, c.x * c.x));
        float t21 = fmaf(c.y, c.y, fmaf(e.x, e.x, e.y * e.y));
        s[2 * threadIdx.x + 0] = make_float4(a.x, a.y, c.x, t20);
        s[2 * threadIdx.x + 1] = make_float4(c.y, e.x, e.y, t21);
    }
    __syncthreads();

    if (!isrep) {
        const int q0 = qblk * (BLK * QCH) + threadIdx.x;
        float nx[QCH], ny[QCH], nz[QCH], q2[QCH], mn[QCH];
        #pragma unroll
        for (int k = 0; k < QCH; ++k) {
            const float* q = qbase + ((size_t)b * NPTS + q0 + k * BLK) * 3;
            float qx = q[0], qy = q[1], qz = q[2];
            q2[k] = fmaf(qx, qx, fmaf(qy, qy, qz * qz));
            nx[k] = -2.f * qx; ny[k] = -2.f * qy; nz[k] = -2.f * qz;
            mn[k] = FLT_MAX;
        }
        #pragma unroll 4
        for (int j = 0; j < TPTS; ++j) {
            float4 t = s[j];
            #pragma unroll
            for (int k = 0; k < QCH; ++k)
                mn[k] = fminf(mn[k],
                    fmaf(nx[k], t.x, fmaf(ny[k], t.y, fmaf(nz[k], t.z, t.w))));
        }
        float* row = minseg + (size_t)seg * NCH + (type * BATCH + b) * NPTS;
        #pragma unroll
        for (int k = 0; k < QCH; ++k)
            row[q0 + k * BLK] = mn[k] + q2[k];
    } else {
        const int q0 = qblk * (BLK * QR) + threadIdx.x;
        float nx[QR], ny[QR], nz[QR], q2[QR];
        float m0[QR], m1[QR], m2[QR], m3[QR];
        int qk[QR];
        #pragma unroll
        for (int k = 0; k < QR; ++k) {
            qk[k] = q0 + k * BLK;
            const float* q = qbase + ((size_t)b * NPTS + qk[k]) * 3;
            float qx = q[0], qy = q[1], qz = q[2];
            q2[k] = fmaf(qx, qx, fmaf(qy, qy, qz * qz));
            nx[k] = -2.f * qx; ny[k] = -2.f * qy; nz[k] = -2.f * qz;
            m0[k] = m1[k] = m2[k] = m3[k] = FLT_MAX;
        }
        const int base = seg * TPTS;
        // self can only appear when this segment overlaps this qblk's queries
        if ((seg >> 4) == qblk) {
            #pragma unroll 2
            for (int j = 0; j < TPTS; ++j) {
                float4 t = s[j];
                #pragma unroll
                for (int k = 0; k < QR; ++k) {
                    float h = fmaf(nx[k], t.x, fmaf(ny[k], t.y, fmaf(nz[k], t.z, t.w)));
                    h = (base + j == qk[k]) ? FLT_MAX : h;   // exclude self
                    float n0 = fminf(m0[k], h);  float u0 = fmaxf(m0[k], h);
                    float n1 = fminf(m1[k], u0); float u1 = fmaxf(m1[k], u0);
                    float n2 = fminf(m2[k], u1); float u2 = fmaxf(m2[k], u1);
                    float n3 = fminf(m3[k], u2);
                    m0[k] = n0; m1[k] = n1; m2[k] = n2; m3[k] = n3;
                }
            }
        } else {
            #pragma unroll 2
            for (int j = 0; j < TPTS; ++j) {
                float4 t = s[j];
                #pragma unroll
                for (int k = 0; k < QR; ++k) {
                    float h = fmaf(nx[k], t.x, fmaf(ny[k], t.y, fmaf(nz[k], t.z, t.w)));
                    float n0 = fminf(m0[k], h);  float u0 = fmaxf(m0[k], h);
                    float n1 = fminf(m1[k], u0); float u1 = fmaxf(m1[k], u0);
                    float n2 = fminf(m2[k], u1); float u2 = fmaxf(m2[k], u1);
                    float n3 = fminf(m3[k], u2);
                    m0[k] = n0; m1[k] = n1; m2[k] = n2; m3[k] = n3;
                }
            }
        }
        #pragma unroll
        for (int k = 0; k < QR; ++k)
            top4[(size_t)seg * NQ + b * NPTS + qk[k]] =
                make_float4(m0[k] + q2[k], m1[k] + q2[k], m2[k] + q2[k], m3[k] + q2[k]);
    }
}

// 192 blocks: [0,128) chamfer sum; [128,192) repulsion merge+eval.
// Last block (fenced atomic counter) finalizes both outputs.
__global__ __launch_bounds__(BLK) void merge_kernel(
    const float* __restrict__ minseg, const float4* __restrict__ top4,
    unsigned int* __restrict__ hdr, float* __restrict__ out)
{
    __shared__ float warr[BLK / 64];
    float contrib;
    int which;
    if (blockIdx.x < NCH / BLK) {
        int i = blockIdx.x * BLK + threadIdx.x;            // [0, 32768)
        float m = minseg[i];
        #pragma unroll 8
        for (int sg = 1; sg < SEGN; ++sg)
            m = fminf(m, minseg[(size_t)sg * NCH + i]);
        contrib = fmaxf(m, 0.f);                           // clamp as in reference
        which = 0;
    } else {
        int i = (blockIdx.x - NCH / BLK) * BLK + threadIdx.x;  // [0, 16384)
        float m0 = FLT_MAX, m1 = FLT_MAX, m2 = FLT_MAX, m3 = FLT_MAX;
        #pragma unroll 4
        for (int sg = 0; sg < SEGN; ++sg) {
            float4 v = top4[(size_t)sg * NQ + i];
            const float vals[4] = {v.x, v.y, v.z, v.w};
            #pragma unroll
            for (int k = 0; k < 4; ++k) {
                float h = vals[k];
                float n0 = fminf(m0, h);  float u0 = fmaxf(m0, h);
                float n1 = fminf(m1, u0); float u1 = fmaxf(m1, u0);
                float n2 = fminf(m2, u1); float u2 = fmaxf(m2, u1);
                float n3 = fminf(m3, u2);
                m0 = n0; m1 = n1; m2 = n2; m3 = n3;
            }
        }
        contrib = 0.f;
        const float ms[4] = {m0, m1, m2, m3};
        #pragma unroll
        for (int k = 0; k < 4; ++k) {
            float d2 = fmaxf(ms[k], EPS_C);
            float d  = sqrtf(d2);
            contrib += (RADIUS_C - d) * expf(-d2 * (1.f / H2));
        }
        which = 1;
    }
    #pragma unroll
    for (int off = 32; off > 0; off >>= 1)
        contrib += __shfl_down(contrib, off, 64);
    if ((threadIdx.x & 63) == 0) warr[threadIdx.x >> 6] = contrib;
    __syncthreads();
    if (threadIdx.x == 0) {
        float bs = warr[0] + warr[1] + warr[2] + warr[3];
        float* accum = (float*)hdr;
        atomicAdd(&accum[which], bs);
        __threadfence();
        unsigned int old = atomicAdd(&hdr[2], 1u);
        if (old == 191u) {                                  // last block finalizes
            float a0 = atomicAdd(&accum[0], 0.f);           // coherent read
            float a1 = atomicAdd(&accum[1], 0.f);
            out[0] = 100.f * a0 * (1.f / NQ);
            out[1] = a1 * (1.f / (NQ * 4));
        }
    }
}

extern "C" void kernel_launch(void* const* d_in, const int* in_sizes, int n_in,
                              void* d_out, int out_size, void* d_ws, size_t ws_size,
                              hipStream_t stream)
{
    const float* pred = (const float*)d_in[0];
    const float* gt   = (const float*)d_in[1];

    unsigned int* hdr    = (unsigned int*)d_ws;
    float*        minseg = (float*)((char*)d_ws + 16);
    float4*       top4   = (float4*)((char*)d_ws + 16 + (size_t)SEGN * NCH * sizeof(float));

    partial_kernel<<<2048, BLK, 0, stream>>>(pred, gt, minseg, top4, hdr);
    merge_kernel<<<192, BLK, 0, stream>>>(minseg, top4, hdr, (float*)d_out);
}

// Round 7
// 111.686 us; speedup vs baseline: 1.0127x; 1.0127x over previous
//
#include <hip/hip_runtime.h>
#include <float.h>
#include <math.h>

#define BATCH 4
#define NPTS 4096
#define BLK 256
#define QCH 4                      // queries per thread (chamfer)
#define SEG_CH 32                  // chamfer target segments (128 pts each)
#define TPTS_CH (NPTS / SEG_CH)    // 128
#define SEG_R 8                    // repulsion target segments (512 pts each)
#define TPTS_R (NPTS / SEG_R)      // 512
#define H2 (0.03f * 0.03f)
#define RADIUS_C 0.07f
#define EPS_C 1e-12f
#define NQ (BATCH * NPTS)          // 16384
#define NCH (2 * NQ)               // 32768 chamfer (type,b,q) rows

// d_ws layout (6 MB total -> stays L2/L3-resident, R5's 24 MB spilled to HBM):
//   hdr    : float accum[2] + uint cnt + pad (16 B)   @ 0   (zeroed by blk(0,0))
//   minseg : float [SEG_CH][NCH]   (4 MB)             @ 16
//   top4   : float4[SEG_R][NQ]     (2 MB)             @ 16 + 4 MB
//
// Model (R5 post-mortem): time ~= wave-VALU-insts/SIMD x ~4.3 cyc (execute-
// bound, verified vs R1/R4/R5). So: minimize instructions per pair.
//   chamfer: 2 targets/iter -> fmin(fmin(m,h0),h1) fuses to v_min3_f32.
//   repulsion: wave-uniform __any(h<m3) skips the 7-op insert (~60% taken).

// repulsion inner loop; EXCL = compare-and-mask self (only 1/8 blocks overlap)
template <bool EXCL>
__device__ __forceinline__ void rep_loop(
    const float4* __restrict__ s, int base, int qi,
    float nx, float ny, float nz,
    float& m0, float& m1, float& m2, float& m3)
{
    for (int j = 0; j < TPTS_R; ++j) {
        float4 t = s[j];
        float h = fmaf(nx, t.x, fmaf(ny, t.y, fmaf(nz, t.z, t.w)));
        if (EXCL) h = (base + j == qi) ? FLT_MAX : h;      // exclude self
        if (__any(h < m3)) {                                // wave-uniform branch
            float n0 = fminf(m0, h);  float u0 = fmaxf(m0, h);
            float n1 = fminf(m1, u0); float u1 = fmaxf(m1, u0);
            float n2 = fminf(m2, u1); float u2 = fmaxf(m2, u1);
            float n3 = fminf(m3, u2);
            m0 = n0; m1 = n1; m2 = n2; m3 = n3;
        }
    }
}

// grid = (128, 12): blockIdx.y = type*4 + b; type 0 pred->gt, 1 gt->pred, 2 rep.
// chamfer blocks: x = qblk(4) + 4*seg(32); repulsion: x = qblk(16) + 16*seg(8).
__global__ __launch_bounds__(BLK) void partial_kernel(
    const float* __restrict__ pred, const float* __restrict__ gt,
    float* __restrict__ minseg, float4* __restrict__ top4,
    unsigned int* __restrict__ hdr)
{
    __shared__ float4 s[TPTS_R];   // (x, y, z, |t|^2); chamfer uses first 128

    if (blockIdx.x == 0 && blockIdx.y == 0 && threadIdx.x < 4)
        hdr[threadIdx.x] = 0u;     // zero accum[2]+cnt for merge

    const int type = blockIdx.y >> 2;
    const int b    = blockIdx.y & 3;

    const float* qbase = (type == 1) ? gt : pred;
    const float* tbase = (type == 0) ? gt : pred;

    if (type < 2) {
        const int qblk = blockIdx.x & 3;
        const int seg  = blockIdx.x >> 2;
        // stage 128 targets: first wave, 2 points/thread, |t|^2 on the fly
        if (threadIdx.x < 64) {
            const float2* g2 = (const float2*)(tbase + ((size_t)b * NPTS + seg * TPTS_CH) * 3);
            float2 a = g2[3 * threadIdx.x + 0];
            float2 c = g2[3 * threadIdx.x + 1];
            float2 e = g2[3 * threadIdx.x + 2];
            float t20 = fmaf(a.x, a.x, fmaf(a.y, a.y, c.x * c.x));
            float t21 = fmaf(c.y, c.y, fmaf(e.x, e.x, e.y * e.y));
            s[2 * threadIdx.x + 0] = make_float4(a.x, a.y, c.x, t20);
            s[2 * threadIdx.x + 1] = make_float4(c.y, e.x, e.y, t21);
        }
        __syncthreads();

        const int q0 = qblk * (BLK * QCH) + threadIdx.x;
        float nx[QCH], ny[QCH], nz[QCH], q2[QCH], mn[QCH];
        #pragma unroll
        for (int k = 0; k < QCH; ++k) {
            const float* q = qbase + ((size_t)b * NPTS + q0 + k * BLK) * 3;
            float qx = q[0], qy = q[1], qz = q[2];
            q2[k] = fmaf(qx, qx, fmaf(qy, qy, qz * qz));
            nx[k] = -2.f * qx; ny[k] = -2.f * qy; nz[k] = -2.f * qz;
            mn[k] = FLT_MAX;
        }
        #pragma unroll 2
        for (int j = 0; j < TPTS_CH; j += 2) {
            float4 t0 = s[j], t1 = s[j + 1];
            #pragma unroll
            for (int k = 0; k < QCH; ++k) {
                float h0 = fmaf(nx[k], t0.x, fmaf(ny[k], t0.y, fmaf(nz[k], t0.z, t0.w)));
                float h1 = fmaf(nx[k], t1.x, fmaf(ny[k], t1.y, fmaf(nz[k], t1.z, t1.w)));
                mn[k] = fminf(fminf(mn[k], h0), h1);       // -> v_min3_f32
            }
        }
        float* row = minseg + (size_t)seg * NCH + (type * BATCH + b) * NPTS;
        #pragma unroll
        for (int k = 0; k < QCH; ++k)
            row[q0 + k * BLK] = mn[k] + q2[k];
    } else {
        const int qblk = blockIdx.x & 15;
        const int seg  = blockIdx.x >> 4;
        // stage 512 targets: all threads, 2 points/thread
        {
            const float2* g2 = (const float2*)(tbase + ((size_t)b * NPTS + seg * TPTS_R) * 3);
            float2 a = g2[3 * threadIdx.x + 0];
            float2 c = g2[3 * threadIdx.x + 1];
            float2 e = g2[3 * threadIdx.x + 2];
            float t20 = fmaf(a.x, a.x, fmaf(a.y, a.y, c.x * c.x));
            float t21 = fmaf(c.y, c.y, fmaf(e.x, e.x, e.y * e.y));
            s[2 * threadIdx.x + 0] = make_float4(a.x, a.y, c.x, t20);
            s[2 * threadIdx.x + 1] = make_float4(c.y, e.x, e.y, t21);
        }
        __syncthreads();

        const int qi = qblk * BLK + threadIdx.x;
        const float* q = qbase + ((size_t)b * NPTS + qi) * 3;
        const float qx = q[0], qy = q[1], qz = q[2];
        const float q2 = fmaf(qx, qx, fmaf(qy, qy, qz * qz));
        const float nx = -2.f * qx, ny = -2.f * qy, nz = -2.f * qz;

        float m0 = FLT_MAX, m1 = FLT_MAX, m2 = FLT_MAX, m3 = FLT_MAX;
        const int base = seg * TPTS_R;
        // queries of this qblk: [qblk*256, qblk*256+256); overlap iff qblk>>1==seg
        if ((qblk >> 1) == seg)
            rep_loop<true >(s, base, qi, nx, ny, nz, m0, m1, m2, m3);
        else
            rep_loop<false>(s, base, qi, nx, ny, nz, m0, m1, m2, m3);

        top4[(size_t)seg * NQ + b * NPTS + qi] =
            make_float4(m0 + q2, m1 + q2, m2 + q2, m3 + q2);
    }
}

// 192 blocks: [0,128) chamfer sum; [128,192) repulsion merge+eval.
// Last block (fenced atomic counter) finalizes both outputs.
__global__ __launch_bounds__(BLK) void merge_kernel(
    const float* __restrict__ minseg, const float4* __restrict__ top4,
    unsigned int* __restrict__ hdr, float* __restrict__ out)
{
    __shared__ float warr[BLK / 64];
    float contrib;
    int which;
    if (blockIdx.x < NCH / BLK) {
        int i = blockIdx.x * BLK + threadIdx.x;            // [0, 32768)
        float m = minseg[i];
        #pragma unroll
        for (int sg = 1; sg < SEG_CH; ++sg)
            m = fminf(m, minseg[(size_t)sg * NCH + i]);
        contrib = fmaxf(m, 0.f);                           // clamp as in reference
        which = 0;
    } else {
        int i = (blockIdx.x - NCH / BLK) * BLK + threadIdx.x;  // [0, 16384)
        float m0 = FLT_MAX, m1 = FLT_MAX, m2 = FLT_MAX, m3 = FLT_MAX;
        #pragma unroll
        for (int sg = 0; sg < SEG_R; ++sg) {
            float4 v = top4[(size_t)sg * NQ + i];
            const float vals[4] = {v.x, v.y, v.z, v.w};
            #pragma unroll
            for (int k = 0; k < 4; ++k) {
                float h = vals[k];
                float n0 = fminf(m0, h);  float u0 = fmaxf(m0, h);
                float n1 = fminf(m1, u0); float u1 = fmaxf(m1, u0);
                float n2 = fminf(m2, u1); float u2 = fmaxf(m2, u1);
                float n3 = fminf(m3, u2);
                m0 = n0; m1 = n1; m2 = n2; m3 = n3;
            }
        }
        contrib = 0.f;
        const float ms[4] = {m0, m1, m2, m3};
        #pragma unroll
        for (int k = 0; k < 4; ++k) {
            float d2 = fmaxf(ms[k], EPS_C);
            float d  = sqrtf(d2);
            contrib += (RADIUS_C - d) * expf(-d2 * (1.f / H2));
        }
        which = 1;
    }
    #pragma unroll
    for (int off = 32; off > 0; off >>= 1)
        contrib += __shfl_down(contrib, off, 64);
    if ((threadIdx.x & 63) == 0) warr[threadIdx.x >> 6] = contrib;
    __syncthreads();
    if (threadIdx.x == 0) {
        float bs = warr[0] + warr[1] + warr[2] + warr[3];
        float* accum = (float*)hdr;
        atomicAdd(&accum[which], bs);
        __threadfence();
        unsigned int old = atomicAdd(&hdr[2], 1u);
        if (old == 191u) {                                  // last block finalizes
            float a0 = atomicAdd(&accum[0], 0.f);           // coherent read
            float a1 = atomicAdd(&accum[1], 0.f);
            out[0] = 100.f * a0 * (1.f / NQ);
            out[1] = a1 * (1.f / (NQ * 4));
        }
    }
}

extern "C" void kernel_launch(void* const* d_in, const int* in_sizes, int n_in,
                              void* d_out, int out_size, void* d_ws, size_t ws_size,
                              hipStream_t stream)
{
    const float* pred = (const float*)d_in[0];
    const float* gt   = (const float*)d_in[1];

    unsigned int* hdr    = (unsigned int*)d_ws;
    float*        minseg = (float*)((char*)d_ws + 16);
    float4*       top4   = (float4*)((char*)d_ws + 16 + (size_t)SEG_CH * NCH * sizeof(float));

    dim3 grid(128, 3 * BATCH);   // 1536 blocks
    partial_kernel<<<grid, BLK, 0, stream>>>(pred, gt, minseg, top4, hdr);
    merge_kernel<<<192, BLK, 0, stream>>>(minseg, top4, hdr, (float*)d_out);
}

// Round 8
// 104.375 us; speedup vs baseline: 1.0837x; 1.0700x over previous
//
#include <hip/hip_runtime.h>
#include <float.h>
#include <math.h>

#define BATCH 4
#define NPTS 4096
#define BLK 256
#define QCH 4                      // queries per thread (chamfer)
#define SEG_CH 32                  // chamfer target segments (128 pts each)
#define TPTS_CH (NPTS / SEG_CH)    // 128
#define SEG_R 8                    // repulsion target segments (512 pts each)
#define TPTS_R (NPTS / SEG_R)      // 512
#define H2 (0.03f * 0.03f)
#define RADIUS_C 0.07f
#define EPS_C 1e-12f
#define T2 0.05f                   // repulsion d^2 cutoff: excluded contribs ~1e-25
#define NQ (BATCH * NPTS)          // 16384
#define NCH (2 * NQ)               // 32768 chamfer (type,b,q) rows

// d_ws layout (6 MB -> L2/L3-resident; R5's 24 MB spilled to HBM):
//   hdr    : float accum[2] + uint cnt + pad (16 B)   @ 0   (zeroed by blk(0,0))
//   minseg : float [SEG_CH][NCH]   (4 MB)             @ 16
//   top4   : float4[SEG_R][NQ]     (2 MB)             @ 16 + 4 MB
//
// d2 = (|t|^2 - 2 q.t) + |q|^2; loops track h = |t|^2 - 2 q.t via n = -2q.
// R6 post-mortem: a FLT_MAX-initialized top-4 makes the __any gate ~85% taken
// (P ~ 256/j). Fix: init m0..m3 = T2 - |q|^2 so the gate fires only when some
// lane sees d^2 < T2=0.05 (~10% of iters). Neighbors beyond T2 contribute
// |(R-d)e^{-d2/H2}| <= 1e-25 -- far below output thresholds.

template <bool EXCL>
__device__ __forceinline__ void rep_loop(
    const float4* __restrict__ s, int base, int qi,
    float nx, float ny, float nz,
    float& m0, float& m1, float& m2, float& m3)
{
    #pragma unroll 2
    for (int j = 0; j < TPTS_R; ++j) {
        float4 t = s[j];
        float h = fmaf(nx, t.x, fmaf(ny, t.y, fmaf(nz, t.z, t.w)));
        if (EXCL) h = (base + j == qi) ? FLT_MAX : h;      // exclude self
        if (__any(h < m3)) {                                // ~10% taken now
            float n0 = fminf(m0, h);  float u0 = fmaxf(m0, h);
            float n1 = fminf(m1, u0); float u1 = fmaxf(m1, u0);
            float n2 = fminf(m2, u1); float u2 = fmaxf(m2, u1);
            float n3 = fminf(m3, u2);
            m0 = n0; m1 = n1; m2 = n2; m3 = n3;
        }
    }
}

// grid = (128, 12): blockIdx.y = type*4 + b; type 0 pred->gt, 1 gt->pred, 2 rep.
// chamfer blocks: x = qblk(4) + 4*seg(32); repulsion: x = qblk(16) + 16*seg(8).
__global__ __launch_bounds__(BLK) void partial_kernel(
    const float* __restrict__ pred, const float* __restrict__ gt,
    float* __restrict__ minseg, float4* __restrict__ top4,
    unsigned int* __restrict__ hdr)
{
    __shared__ float4 s[TPTS_R];   // (x, y, z, |t|^2); chamfer uses first 128

    if (blockIdx.x == 0 && blockIdx.y == 0 && threadIdx.x < 4)
        hdr[threadIdx.x] = 0u;     // zero accum[2]+cnt for merge

    const int type = blockIdx.y >> 2;
    const int b    = blockIdx.y & 3;

    const float* qbase = (type == 1) ? gt : pred;
    const float* tbase = (type == 0) ? gt : pred;

    if (type < 2) {
        const int qblk = blockIdx.x & 3;
        const int seg  = blockIdx.x >> 2;
        // stage 128 targets: first wave, 2 points/thread, |t|^2 on the fly
        if (threadIdx.x < 64) {
            const float2* g2 = (const float2*)(tbase + ((size_t)b * NPTS + seg * TPTS_CH) * 3);
            float2 a = g2[3 * threadIdx.x + 0];
            float2 c = g2[3 * threadIdx.x + 1];
            float2 e = g2[3 * threadIdx.x + 2];
            float t20 = fmaf(a.x, a.x, fmaf(a.y, a.y, c.x * c.x));
            float t21 = fmaf(c.y, c.y, fmaf(e.x, e.x, e.y * e.y));
            s[2 * threadIdx.x + 0] = make_float4(a.x, a.y, c.x, t20);
            s[2 * threadIdx.x + 1] = make_float4(c.y, e.x, e.y, t21);
        }
        __syncthreads();

        const int q0 = qblk * (BLK * QCH) + threadIdx.x;
        float nx[QCH], ny[QCH], nz[QCH], q2[QCH], mn[QCH];
        #pragma unroll
        for (int k = 0; k < QCH; ++k) {
            const float* q = qbase + ((size_t)b * NPTS + q0 + k * BLK) * 3;
            float qx = q[0], qy = q[1], qz = q[2];
            q2[k] = fmaf(qx, qx, fmaf(qy, qy, qz * qz));
            nx[k] = -2.f * qx; ny[k] = -2.f * qy; nz[k] = -2.f * qz;
            mn[k] = FLT_MAX;
        }
        #pragma unroll 2
        for (int j = 0; j < TPTS_CH; j += 2) {
            float4 t0 = s[j], t1 = s[j + 1];
            #pragma unroll
            for (int k = 0; k < QCH; ++k) {
                float h0 = fmaf(nx[k], t0.x, fmaf(ny[k], t0.y, fmaf(nz[k], t0.z, t0.w)));
                float h1 = fmaf(nx[k], t1.x, fmaf(ny[k], t1.y, fmaf(nz[k], t1.z, t1.w)));
                mn[k] = fminf(fminf(mn[k], h0), h1);       // -> v_min3_f32
            }
        }
        float* row = minseg + (size_t)seg * NCH + (type * BATCH + b) * NPTS;
        #pragma unroll
        for (int k = 0; k < QCH; ++k)
            row[q0 + k * BLK] = mn[k] + q2[k];
    } else {
        const int qblk = blockIdx.x & 15;
        const int seg  = blockIdx.x >> 4;
        // stage 512 targets: all threads, 2 points/thread
        {
            const float2* g2 = (const float2*)(tbase + ((size_t)b * NPTS + seg * TPTS_R) * 3);
            float2 a = g2[3 * threadIdx.x + 0];
            float2 c = g2[3 * threadIdx.x + 1];
            float2 e = g2[3 * threadIdx.x + 2];
            float t20 = fmaf(a.x, a.x, fmaf(a.y, a.y, c.x * c.x));
            float t21 = fmaf(c.y, c.y, fmaf(e.x, e.x, e.y * e.y));
            s[2 * threadIdx.x + 0] = make_float4(a.x, a.y, c.x, t20);
            s[2 * threadIdx.x + 1] = make_float4(c.y, e.x, e.y, t21);
        }
        __syncthreads();

        const int qi = qblk * BLK + threadIdx.x;
        const float* q = qbase + ((size_t)b * NPTS + qi) * 3;
        const float qx = q[0], qy = q[1], qz = q[2];
        const float q2 = fmaf(qx, qx, fmaf(qy, qy, qz * qz));
        const float nx = -2.f * qx, ny = -2.f * qy, nz = -2.f * qz;

        // h-space threshold init: h < T2 - q2  <=>  d2 < T2
        float m0 = T2 - q2, m1 = m0, m2 = m0, m3 = m0;
        const int base = seg * TPTS_R;
        // queries of this qblk: [qblk*256, qblk*256+256); overlap iff qblk>>1==seg
        if ((qblk >> 1) == seg)
            rep_loop<true >(s, base, qi, nx, ny, nz, m0, m1, m2, m3);
        else
            rep_loop<false>(s, base, qi, nx, ny, nz, m0, m1, m2, m3);

        top4[(size_t)seg * NQ + b * NPTS + qi] =
            make_float4(m0 + q2, m1 + q2, m2 + q2, m3 + q2);
    }
}

// 192 blocks: [0,128) chamfer sum; [128,192) repulsion merge+eval.
// Last block (fenced atomic counter) finalizes both outputs.
__global__ __launch_bounds__(BLK) void merge_kernel(
    const float* __restrict__ minseg, const float4* __restrict__ top4,
    unsigned int* __restrict__ hdr, float* __restrict__ out)
{
    __shared__ float warr[BLK / 64];
    float contrib;
    int which;
    if (blockIdx.x < NCH / BLK) {
        int i = blockIdx.x * BLK + threadIdx.x;            // [0, 32768)
        float m = minseg[i];
        #pragma unroll
        for (int sg = 1; sg < SEG_CH; ++sg)
            m = fminf(m, minseg[(size_t)sg * NCH + i]);
        contrib = fmaxf(m, 0.f);                           // clamp as in reference
        which = 0;
    } else {
        int i = (blockIdx.x - NCH / BLK) * BLK + threadIdx.x;  // [0, 16384)
        float m0 = FLT_MAX, m1 = FLT_MAX, m2 = FLT_MAX, m3 = FLT_MAX;
        #pragma unroll
        for (int sg = 0; sg < SEG_R; ++sg) {
            float4 v = top4[(size_t)sg * NQ + i];
            const float vals[4] = {v.x, v.y, v.z, v.w};
            #pragma unroll
            for (int k = 0; k < 4; ++k) {
                float h = vals[k];
                float n0 = fminf(m0, h);  float u0 = fmaxf(m0, h);
                float n1 = fminf(m1, u0); float u1 = fmaxf(m1, u0);
                float n2 = fminf(m2, u1); float u2 = fmaxf(m2, u1);
                float n3 = fminf(m3, u2);
                m0 = n0; m1 = n1; m2 = n2; m3 = n3;
            }
        }
        contrib = 0.f;
        const float ms[4] = {m0, m1, m2, m3};
        #pragma unroll
        for (int k = 0; k < 4; ++k) {
            float d2 = fmaxf(ms[k], EPS_C);
            float d  = sqrtf(d2);
            contrib += (RADIUS_C - d) * expf(-d2 * (1.f / H2));
        }
        which = 1;
    }
    #pragma unroll
    for (int off = 32; off > 0; off >>= 1)
        contrib += __shfl_down(contrib, off, 64);
    if ((threadIdx.x & 63) == 0) warr[threadIdx.x >> 6] = contrib;
    __syncthreads();
    if (threadIdx.x == 0) {
        float bs = warr[0] + warr[1] + warr[2] + warr[3];
        float* accum = (float*)hdr;
        atomicAdd(&accum[which], bs);
        __threadfence();
        unsigned int old = atomicAdd(&hdr[2], 1u);
        if (old == 191u) {                                  // last block finalizes
            float a0 = atomicAdd(&accum[0], 0.f);           // coherent read
            float a1 = atomicAdd(&accum[1], 0.f);
            out[0] = 100.f * a0 * (1.f / NQ);
            out[1] = a1 * (1.f / (NQ * 4));
        }
    }
}

extern "C" void kernel_launch(void* const* d_in, const int* in_sizes, int n_in,
                              void* d_out, int out_size, void* d_ws, size_t ws_size,
                              hipStream_t stream)
{
    const float* pred = (const float*)d_in[0];
    const float* gt   = (const float*)d_in[1];

    unsigned int* hdr    = (unsigned int*)d_ws;
    float*        minseg = (float*)((char*)d_ws + 16);
    float4*       top4   = (float4*)((char*)d_ws + 16 + (size_t)SEG_CH * NCH * sizeof(float));

    dim3 grid(128, 3 * BATCH);   // 1536 blocks
    partial_kernel<<<grid, BLK, 0, stream>>>(pred, gt, minseg, top4, hdr);
    merge_kernel<<<192, BLK, 0, stream>>>(minseg, top4, hdr, (float*)d_out);
}

// Round 9
// 92.940 us; speedup vs baseline: 1.2170x; 1.1230x over previous
//
#include <hip/hip_runtime.h>
#include <float.h>
#include <math.h>

#define BATCH 4
#define NPTS 4096
#define BLK 256
#define QCH 4                      // queries/thread, chamfer
#define QR 2                       // queries/thread, repulsion
#define SEG_CH 32                  // chamfer segments (128 pts)
#define TPTS_CH (NPTS / SEG_CH)    // 128
#define SEG_R 32                   // repulsion segments (128 pts)
#define TPTS_R (NPTS / SEG_R)      // 128
#define H2 (0.03f * 0.03f)
#define RADIUS_C 0.07f
#define EPS_C 1e-12f
#define T2 0.05f                   // rep d^2 cutoff: excluded contribs ~1e-25
#define NQ (BATCH * NPTS)          // 16384
#define NCH (2 * NQ)               // 32768 chamfer (type,b,q) rows

// d_ws (12 MB):
//   hdr    : float accum[2] + uint cnt + pad (16 B)  @ 0  (zeroed by blk 0)
//   minseg : float [SEG_CH][NCH]   (4 MB)            @ 16
//   top4   : float4[SEG_R][NQ]     (8 MB)            @ 16 + 4 MB
//
// R7 post-mortem: the binder was a repulsion-only TAIL (2 blocks/CU, latency-
// exposed). Fix: uniform 128-target blocks for BOTH phases, interleaved, 2048
// total -> queue stays full, no tail. QR=2 halves rep LDS-reads/pair.
// h = |t|^2 - 2 q.t (reference's expansion); top-4 regs init to T2-|q|^2 so
// the insert gate fires only for d^2 < T2 (~10-20% of iters).

template <bool EXCL>
__device__ __forceinline__ void rep_loop(
    const float4* __restrict__ s, int base, int q0, int q1,
    float nx0, float ny0, float nz0, float nx1, float ny1, float nz1,
    float& a0, float& a1, float& a2, float& a3,
    float& b0, float& b1, float& b2, float& b3)
{
    #pragma unroll 2
    for (int j = 0; j < TPTS_R; ++j) {
        float4 t = s[j];
        float h0 = fmaf(nx0, t.x, fmaf(ny0, t.y, fmaf(nz0, t.z, t.w)));
        float h1 = fmaf(nx1, t.x, fmaf(ny1, t.y, fmaf(nz1, t.z, t.w)));
        if (EXCL) {
            h0 = (base + j == q0) ? FLT_MAX : h0;          // exclude self
            h1 = (base + j == q1) ? FLT_MAX : h1;
        }
        if (__any((h0 < a3) | (h1 < b3))) {                // wave-uniform, rare
            float n0 = fminf(a0, h0);  float u0 = fmaxf(a0, h0);
            float n1 = fminf(a1, u0);  float u1 = fmaxf(a1, u0);
            float n2 = fminf(a2, u1);  float u2 = fmaxf(a2, u1);
            float n3 = fminf(a3, u2);
            a0 = n0; a1 = n1; a2 = n2; a3 = n3;
            float p0 = fminf(b0, h1);  float w0 = fmaxf(b0, h1);
            float p1 = fminf(b1, w0);  float w1 = fmaxf(b1, w0);
            float p2 = fminf(b2, w1);  float w2 = fmaxf(b2, w1);
            float p3 = fminf(b3, w2);
            b0 = p0; b1 = p1; b2 = p2; b3 = p3;
        }
    }
}

// 2048 blocks: even bid = chamfer (qblk4 x type2 x b4 x seg32 = 1024),
//              odd  bid = repulsion (qblk8 x b4 x seg32 = 1024).
__global__ __launch_bounds__(BLK) void partial_kernel(
    const float* __restrict__ pred, const float* __restrict__ gt,
    float* __restrict__ minseg, float4* __restrict__ top4,
    unsigned int* __restrict__ hdr)
{
    __shared__ float4 s[TPTS_R];   // 128 x (x,y,z,|t|^2) = 2 KB

    if (blockIdx.x == 0 && threadIdx.x < 4)
        hdr[threadIdx.x] = 0u;     // zero accum[2]+cnt for merge

    const int bid   = blockIdx.x;
    const int isrep = bid & 1;
    const int id    = bid >> 1;    // [0,1024)

    int type, b, qblk, seg;
    if (!isrep) {
        qblk = id & 3; type = (id >> 2) & 1; b = (id >> 3) & 3; seg = id >> 5;
    } else {
        qblk = id & 7; type = 2;             b = (id >> 3) & 3; seg = id >> 5;
    }
    const float* qbase = (type == 1) ? gt : pred;
    const float* tbase = (type == 0) ? gt : pred;

    // stage 128 targets: threads 0..63, 2 points each, |t|^2 on the fly
    if (threadIdx.x < 64) {
        const float2* g2 = (const float2*)(tbase + ((size_t)b * NPTS + seg * TPTS_R) * 3);
        float2 a = g2[3 * threadIdx.x + 0];
        float2 c = g2[3 * threadIdx.x + 1];
        float2 e = g2[3 * threadIdx.x + 2];
        float t20 = fmaf(a.x, a.x, fmaf(a.y, a.y, c.x * c.x));
        float t21 = fmaf(c.y, c.y, fmaf(e.x, e.x, e.y * e.y));
        s[2 * threadIdx.x + 0] = make_float4(a.x, a.y, c.x, t20);
        s[2 * threadIdx.x + 1] = make_float4(c.y, e.x, e.y, t21);
    }
    __syncthreads();

    if (!isrep) {
        const int q0 = qblk * (BLK * QCH) + threadIdx.x;
        float nx[QCH], ny[QCH], nz[QCH], q2[QCH], mn[QCH];
        #pragma unroll
        for (int k = 0; k < QCH; ++k) {
            const float* q = qbase + ((size_t)b * NPTS + q0 + k * BLK) * 3;
            float qx = q[0], qy = q[1], qz = q[2];
            q2[k] = fmaf(qx, qx, fmaf(qy, qy, qz * qz));
            nx[k] = -2.f * qx; ny[k] = -2.f * qy; nz[k] = -2.f * qz;
            mn[k] = FLT_MAX;
        }
        #pragma unroll 2
        for (int j = 0; j < TPTS_CH; j += 2) {
            float4 t0 = s[j], t1 = s[j + 1];
            #pragma unroll
            for (int k = 0; k < QCH; ++k) {
                float h0 = fmaf(nx[k], t0.x, fmaf(ny[k], t0.y, fmaf(nz[k], t0.z, t0.w)));
                float h1 = fmaf(nx[k], t1.x, fmaf(ny[k], t1.y, fmaf(nz[k], t1.z, t1.w)));
                mn[k] = fminf(fminf(mn[k], h0), h1);       // -> v_min3_f32
            }
        }
        float* row = minseg + (size_t)seg * NCH + (type * BATCH + b) * NPTS;
        #pragma unroll
        for (int k = 0; k < QCH; ++k)
            row[q0 + k * BLK] = mn[k] + q2[k];
    } else {
        const int q0 = qblk * (BLK * QR) + threadIdx.x;
        const int q1 = q0 + BLK;
        const float* qa = qbase + ((size_t)b * NPTS + q0) * 3;
        const float* qb = qbase + ((size_t)b * NPTS + q1) * 3;
        float qx0 = qa[0], qy0 = qa[1], qz0 = qa[2];
        float qx1 = qb[0], qy1 = qb[1], qz1 = qb[2];
        float q20 = fmaf(qx0, qx0, fmaf(qy0, qy0, qz0 * qz0));
        float q21 = fmaf(qx1, qx1, fmaf(qy1, qy1, qz1 * qz1));
        float nx0 = -2.f * qx0, ny0 = -2.f * qy0, nz0 = -2.f * qz0;
        float nx1 = -2.f * qx1, ny1 = -2.f * qy1, nz1 = -2.f * qz1;

        // h-space cutoff init: h < T2 - q2  <=>  d2 < T2
        float a0 = T2 - q20, a1 = a0, a2 = a0, a3 = a0;
        float b0 = T2 - q21, b1 = b0, b2 = b0, b3 = b0;
        const int base = seg * TPTS_R;
        // queries [qblk*512, +512) overlap targets [seg*128, +128) iff seg>>2==qblk
        if ((seg >> 2) == qblk)
            rep_loop<true >(s, base, q0, q1, nx0, ny0, nz0, nx1, ny1, nz1,
                            a0, a1, a2, a3, b0, b1, b2, b3);
        else
            rep_loop<false>(s, base, q0, q1, nx0, ny0, nz0, nx1, ny1, nz1,
                            a0, a1, a2, a3, b0, b1, b2, b3);

        float4* dst = top4 + (size_t)seg * NQ + b * NPTS;
        dst[q0] = make_float4(a0 + q20, a1 + q20, a2 + q20, a3 + q20);
        dst[q1] = make_float4(b0 + q21, b1 + q21, b2 + q21, b3 + q21);
    }
}

// 192 blocks: [0,128) chamfer sum; [128,192) repulsion merge+eval.
// Last block (fenced atomic counter) finalizes both outputs.
__global__ __launch_bounds__(BLK) void merge_kernel(
    const float* __restrict__ minseg, const float4* __restrict__ top4,
    unsigned int* __restrict__ hdr, float* __restrict__ out)
{
    __shared__ float warr[BLK / 64];
    float contrib;
    int which;
    if (blockIdx.x < NCH / BLK) {
        int i = blockIdx.x * BLK + threadIdx.x;            // [0, 32768)
        float m = minseg[i];
        #pragma unroll 8
        for (int sg = 1; sg < SEG_CH; ++sg)
            m = fminf(m, minseg[(size_t)sg * NCH + i]);
        contrib = fmaxf(m, 0.f);                           // clamp as in reference
        which = 0;
    } else {
        int i = (blockIdx.x - NCH / BLK) * BLK + threadIdx.x;  // [0, 16384)
        float m0 = FLT_MAX, m1 = FLT_MAX, m2 = FLT_MAX, m3 = FLT_MAX;
        #pragma unroll 4
        for (int sg = 0; sg < SEG_R; ++sg) {
            float4 v = top4[(size_t)sg * NQ + i];
            const float vals[4] = {v.x, v.y, v.z, v.w};
            #pragma unroll
            for (int k = 0; k < 4; ++k) {
                float h = vals[k];
                float n0 = fminf(m0, h);  float u0 = fmaxf(m0, h);
                float n1 = fminf(m1, u0); float u1 = fmaxf(m1, u0);
                float n2 = fminf(m2, u1); float u2 = fmaxf(m2, u1);
                float n3 = fminf(m3, u2);
                m0 = n0; m1 = n1; m2 = n2; m3 = n3;
            }
        }
        contrib = 0.f;
        const float ms[4] = {m0, m1, m2, m3};
        #pragma unroll
        for (int k = 0; k < 4; ++k) {
            float d2 = fmaxf(ms[k], EPS_C);
            float d  = sqrtf(d2);
            contrib += (RADIUS_C - d) * expf(-d2 * (1.f / H2));
        }
        which = 1;
    }
    #pragma unroll
    for (int off = 32; off > 0; off >>= 1)
        contrib += __shfl_down(contrib, off, 64);
    if ((threadIdx.x & 63) == 0) warr[threadIdx.x >> 6] = contrib;
    __syncthreads();
    if (threadIdx.x == 0) {
        float bs = warr[0] + warr[1] + warr[2] + warr[3];
        float* accum = (float*)hdr;
        atomicAdd(&accum[which], bs);
        __threadfence();
        unsigned int old = atomicAdd(&hdr[2], 1u);
        if (old == 191u) {                                  // last block finalizes
            float a0 = atomicAdd(&accum[0], 0.f);           // coherent read
            float a1 = atomicAdd(&accum[1], 0.f);
            out[0] = 100.f * a0 * (1.f / NQ);
            out[1] = a1 * (1.f / (NQ * 4));
        }
    }
}

extern "C" void kernel_launch(void* const* d_in, const int* in_sizes, int n_in,
                              void* d_out, int out_size, void* d_ws, size_t ws_size,
                              hipStream_t stream)
{
    const float* pred = (const float*)d_in[0];
    const float* gt   = (const float*)d_in[1];

    unsigned int* hdr    = (unsigned int*)d_ws;
    float*        minseg = (float*)((char*)d_ws + 16);
    float4*       top4   = (float4*)((char*)d_ws + 16 + (size_t)SEG_CH * NCH * sizeof(float));

    partial_kernel<<<2048, BLK, 0, stream>>>(pred, gt, minseg, top4, hdr);
    merge_kernel<<<192, BLK, 0, stream>>>(minseg, top4, hdr, (float*)d_out);
}